// Round 1
// 227.059 us; speedup vs baseline: 1.0087x; 1.0087x over previous
//
#include <hip/hip_runtime.h>

// DeletionChannel: per batch, drop rows where noise<0.1 && pos < len-1,
// stable-compact kept rows to the front, pad tail with eos one-hot [1,0,...,0].
// B=64, L=4096, V=128, fp32.

// Native clang vector type: __builtin_nontemporal_* requires a real vector
// type, not HIP's struct-based float4.
typedef float vfloat4 __attribute__((ext_vector_type(4)));

// ---------------- Phase 1: build per-output-row source index ----------------
// One block (1024 threads) per batch. Block-wide exclusive scan of keep flags
// inverted into a gather index: src[b][j] = source row for output row j, or
// -1 for eos pad rows. ~5 us total (64 blocks).
__global__ __launch_bounds__(1024) void build_src_kernel(
    const float* __restrict__ noise,   // [B, L]
    const int*   __restrict__ msg_len, // [B]
    int*         __restrict__ src,     // [B, L]
    int L)
{
    const int b   = blockIdx.x;
    const int tid = threadIdx.x;           // 0..1023
    const int len_m1 = msg_len[b] - 1;     // len==0 -> -1 -> no deletions

    const int base = tid * 4;
    const float4 nv = reinterpret_cast<const float4*>(noise + (size_t)b * L)[tid];

    int keep[4];
    keep[0] = !((nv.x < 0.1f) && (base + 0 < len_m1));
    keep[1] = !((nv.y < 0.1f) && (base + 1 < len_m1));
    keep[2] = !((nv.z < 0.1f) && (base + 2 < len_m1));
    keep[3] = !((nv.w < 0.1f) && (base + 3 < len_m1));

    const int c = keep[0] + keep[1] + keep[2] + keep[3];

    // wave-level (64-lane) inclusive scan of per-thread counts
    const int lane = tid & 63;
    const int wave = tid >> 6;             // 0..15
    int val = c;
    #pragma unroll
    for (int off = 1; off < 64; off <<= 1) {
        int up = __shfl_up(val, off, 64);
        if (lane >= off) val += up;
    }

    __shared__ int wave_sums[16];
    __shared__ int wave_offsets[17];
    if (lane == 63) wave_sums[wave] = val;
    __syncthreads();
    if (tid == 0) {
        int acc = 0;
        wave_offsets[0] = 0;
        #pragma unroll
        for (int w = 0; w < 16; ++w) { acc += wave_sums[w]; wave_offsets[w + 1] = acc; }
    }
    __syncthreads();

    const int excl     = wave_offsets[wave] + (val - c);  // exclusive prefix of kept
    const int num_kept = wave_offsets[16];

    int p = excl;
    int* srow = src + (size_t)b * L;
    #pragma unroll
    for (int k = 0; k < 4; ++k) {
        if (keep[k]) { srow[p] = base + k; ++p; }
    }
    for (int j = num_kept + tid; j < L; j += blockDim.x) srow[j] = -1;
}

// ---------------- Phase 2: gather rows / write eos ----------------
// Flat float4 index space: 8.4M float4s, 32 per output row. Each thread
// moves 4 independent float4s (wave-stride 256 within block => every load
// and store instruction is a fully contiguous 1 KiB across the 64-lane
// wave). src indices loaded first (ILP, breaks src->message dep chain).
// Loads stay nontemporal (message is read-once; keep it out of L2/LLC so
// the cache capacity is reserved for the write stream). Stores are now
// CACHED: the 128 MiB output fits in the 256 MiB Infinity Cache, so normal
// stores let LLC absorb the write stream in-kernel and drain lazily after
// the kernel ends, instead of forcing a full HBM write drain inside the
// timed region (NT stores did the latter).
__global__ __launch_bounds__(256) void gather_kernel(
    const vfloat4* __restrict__ message4, // [B*L*32]
    const int*     __restrict__ src,      // [B*L]
    vfloat4*       __restrict__ out4)     // [B*L*32]
{
    const long long f0 = (long long)blockIdx.x * 1024 + threadIdx.x;

    int s[4];
    #pragma unroll
    for (int k = 0; k < 4; ++k) {
        const long long f = f0 + (long long)k * 256;
        s[k] = src[(int)(f >> 5)];
    }

    vfloat4 v[4];
    #pragma unroll
    for (int k = 0; k < 4; ++k) {
        const long long f = f0 + (long long)k * 256;
        const int lane = (int)(f & 31);
        if (s[k] < 0) {
            v[k] = (vfloat4){lane == 0 ? 1.0f : 0.0f, 0.0f, 0.0f, 0.0f};
        } else {
            const int b = (int)(f >> 17);           // f / (4096*32)
            const long long idx = (((long long)b << 12) + s[k]) * 32 + lane;
            v[k] = __builtin_nontemporal_load(message4 + idx);
        }
    }

    #pragma unroll
    for (int k = 0; k < 4; ++k) {
        out4[f0 + (long long)k * 256] = v[k];
    }
}

extern "C" void kernel_launch(void* const* d_in, const int* in_sizes, int n_in,
                              void* d_out, int out_size, void* d_ws, size_t ws_size,
                              hipStream_t stream) {
    const float* message = (const float*)d_in[0];  // [B, L, V]
    const float* noise   = (const float*)d_in[1];  // [B, L]
    const int*   msg_len = (const int*)d_in[2];    // [B]
    float*       out     = (float*)d_out;

    const int B = in_sizes[2];                 // 64
    const int L = in_sizes[1] / B;             // 4096

    int* src = (int*)d_ws;                     // B*L ints = 1 MiB scratch

    build_src_kernel<<<B, 1024, 0, stream>>>(noise, msg_len, src, L);

    const long long total_f4 = (long long)B * L * 32;   // 8388608
    const int blocks = (int)(total_f4 / 1024);          // 8192
    gather_kernel<<<blocks, 256, 0, stream>>>(
        (const vfloat4*)message, src, (vfloat4*)out);
}

// Round 4
// 226.618 us; speedup vs baseline: 1.0107x; 1.0019x over previous
//
#include <hip/hip_runtime.h>

// DeletionChannel: per batch, drop rows where noise<0.1 && pos < len-1,
// stable-compact kept rows to the front, pad tail with eos one-hot [1,0,...,0].
// B=64, L=4096, V=128, fp32.

// Native clang vector type: __builtin_nontemporal_* requires a real vector
// type, not HIP's struct-based float4.
typedef float vfloat4 __attribute__((ext_vector_type(4)));

// ---------------- Phase 1: build per-output-row source index ----------------
// One block (1024 threads) per batch. Block-wide exclusive scan of keep flags
// inverted into a gather index: src[b][j] = source row for output row j, or
// -1 for eos pad rows. ~3-5 us total (64 blocks).
__global__ __launch_bounds__(1024) void build_src_kernel(
    const float* __restrict__ noise,   // [B, L]
    const int*   __restrict__ msg_len, // [B]
    int*         __restrict__ src,     // [B, L]
    int L)
{
    const int b   = blockIdx.x;
    const int tid = threadIdx.x;           // 0..1023
    const int len_m1 = msg_len[b] - 1;     // len==0 -> -1 -> no deletions

    const int base = tid * 4;
    const float4 nv = reinterpret_cast<const float4*>(noise + (size_t)b * L)[tid];

    int keep[4];
    keep[0] = !((nv.x < 0.1f) && (base + 0 < len_m1));
    keep[1] = !((nv.y < 0.1f) && (base + 1 < len_m1));
    keep[2] = !((nv.z < 0.1f) && (base + 2 < len_m1));
    keep[3] = !((nv.w < 0.1f) && (base + 3 < len_m1));

    const int c = keep[0] + keep[1] + keep[2] + keep[3];

    // wave-level (64-lane) inclusive scan of per-thread counts
    const int lane = tid & 63;
    const int wave = tid >> 6;             // 0..15
    int val = c;
    #pragma unroll
    for (int off = 1; off < 64; off <<= 1) {
        int up = __shfl_up(val, off, 64);
        if (lane >= off) val += up;
    }

    __shared__ int wave_sums[16];
    __shared__ int wave_offsets[17];
    if (lane == 63) wave_sums[wave] = val;
    __syncthreads();
    if (tid == 0) {
        int acc = 0;
        wave_offsets[0] = 0;
        #pragma unroll
        for (int w = 0; w < 16; ++w) { acc += wave_sums[w]; wave_offsets[w + 1] = acc; }
    }
    __syncthreads();

    const int excl     = wave_offsets[wave] + (val - c);  // exclusive prefix of kept
    const int num_kept = wave_offsets[16];

    int p = excl;
    int* srow = src + (size_t)b * L;
    #pragma unroll
    for (int k = 0; k < 4; ++k) {
        if (keep[k]) { srow[p] = base + k; ++p; }
    }
    for (int j = num_kept + tid; j < L; j += blockDim.x) srow[j] = -1;
}

// ---------------- Phase 2: gather rows / write eos ----------------
// Flat float4 index space: 8.4M float4s, 32 per output row. Each thread
// moves 8 independent float4s (wave-stride 256 within block => every load
// and store instruction is a fully contiguous 1 KiB across the 64-lane
// wave).
//
// R1 design (third submit — R1/R2 benches were infra failures, audited
// in-bounds and hang-free):
//  - BRANCHLESS load train: instead of `if (s<0) eos else load`, always load
//    from a clamped address (pad rows re-read row 0 of their batch: a
//    broadcast L2 hit, ~5% of rows, negligible HBM) and select eos with a
//    cndmask afterwards. The 8 global_load_dwordx4 now issue back-to-back
//    with no exec-mask branches between them -> deeper MLP per wave.
//  - 32-bit index math everywhere (8.4M float4s < 2^31): shorter dependent
//    address chains (v_add vs v_add_co/v_addc pairs) ahead of each load.
//  - 8 float4s/thread (was 4), 4096 blocks: longer in-flight load train.
//    (Requires total_f4 % 2048 == 0; holds: 64*4096*32 = 8388608 = 4096*2048.)
__global__ __launch_bounds__(256) void gather_kernel(
    const vfloat4* __restrict__ message4, // [B*L*32]
    const int*     __restrict__ src,      // [B*L]
    vfloat4*       __restrict__ out4)     // [B*L*32]
{
    const int f0 = blockIdx.x * 2048 + threadIdx.x;

    int s[8];
    #pragma unroll
    for (int k = 0; k < 8; ++k) {
        s[k] = src[(f0 + k * 256) >> 5];
    }

    vfloat4 v[8];
    #pragma unroll
    for (int k = 0; k < 8; ++k) {
        const int f    = f0 + k * 256;
        const int lane = f & 31;
        const int b    = f >> 17;                     // f / (4096*32)
        const int srow = s[k] < 0 ? 0 : s[k];         // clamp: pad rows read row 0
        const int idx  = ((b << 12) + srow) * 32 + lane;
        v[k] = __builtin_nontemporal_load(message4 + idx);
    }

    #pragma unroll
    for (int k = 0; k < 8; ++k) {
        const int f    = f0 + k * 256;
        const int lane = f & 31;
        const vfloat4 eos = (vfloat4){lane == 0 ? 1.0f : 0.0f, 0.0f, 0.0f, 0.0f};
        out4[f] = (s[k] < 0) ? eos : v[k];
    }
}

extern "C" void kernel_launch(void* const* d_in, const int* in_sizes, int n_in,
                              void* d_out, int out_size, void* d_ws, size_t ws_size,
                              hipStream_t stream) {
    const float* message = (const float*)d_in[0];  // [B, L, V]
    const float* noise   = (const float*)d_in[1];  // [B, L]
    const int*   msg_len = (const int*)d_in[2];    // [B]
    float*       out     = (float*)d_out;

    const int B = in_sizes[2];                 // 64
    const int L = in_sizes[1] / B;             // 4096

    int* src = (int*)d_ws;                     // B*L ints = 1 MiB scratch

    build_src_kernel<<<B, 1024, 0, stream>>>(noise, msg_len, src, L);

    const long long total_f4 = (long long)B * L * 32;   // 8388608
    const int blocks = (int)(total_f4 / 2048);          // 4096
    gather_kernel<<<blocks, 256, 0, stream>>>(
        (const vfloat4*)message, src, (vfloat4*)out);
}